// Round 1
// baseline (1736.745 us; speedup 1.0000x reference)
//
#include <hip/hip_runtime.h>
#include <cstdint>

// Instant-NGP style hash-grid encoder, D=3, L=16, C=2, H=16, PS=2.0, T=2^19.
// Levels 0-2 dense (stride 17/33/65), levels 3-15 hashed (mask 0x7FFFF).
// bound is fixed =1 by setup_inputs -> x01 = (x+1)/2 hardcoded (exact /2).
// NUMERICS: pos = x01*scale + 0.5 MUST be two separately-rounded f32 ops
// (numpy reference semantics). 1 ulp at level 15 = 0.0625 cells -> index /
// frac drift would exceed the 2e-6 absmax threshold. __fmul_rn/__fadd_rn
// block FMA contraction on the critical path.

static constexpr int NLEVELS = 16;
static constexpr uint32_t PRIME1 = 2654435761u;
static constexpr uint32_t PRIME2 = 805459861u;
static constexpr uint32_t HASH_MASK = (1u << 19) - 1u;

__global__ __launch_bounds__(256) void grid_encode_kernel(
    const float* __restrict__ inputs,      // [B,3]
    const float* __restrict__ embeddings,  // [4920,2]  (level 0 rows of full table)
    const float* __restrict__ table,       // [TOTAL-4920,2]
    float* __restrict__ out,               // [B,32]
    int B)
{
    // full-table float2-entry offsets per level
    constexpr uint32_t offs[17] = {
        0u, 4920u, 40864u, 315496u, 839784u, 1364072u, 1888360u, 2412648u,
        2936936u, 3461224u, 3985512u, 4509800u, 5034088u, 5558376u,
        6082664u, 6606952u, 7131240u};

    __shared__ float sIn[768];
    const int tid = threadIdx.x;
    const int b0  = blockIdx.x * 256;

    // coalesced staging of [256,3] inputs through LDS
    {
        const float* gp = inputs + (size_t)b0 * 3;
        const int lim = B * 3 - b0 * 3;
        if (tid       < lim) sIn[tid]       = gp[tid];
        if (tid + 256 < lim) sIn[tid + 256] = gp[tid + 256];
        if (tid + 512 < lim) sIn[tid + 512] = gp[tid + 512];
    }
    __syncthreads();

    const int b = b0 + tid;
    if (b >= B) return;

    // bound = 1: x01 = (x+1)/2 ; add rounds once, *0.5 exact (matches np)
    const float x01 = __fadd_rn(sIn[tid * 3 + 0], 1.0f) * 0.5f;
    const float y01 = __fadd_rn(sIn[tid * 3 + 1], 1.0f) * 0.5f;
    const float z01 = __fadd_rn(sIn[tid * 3 + 2], 1.0f) * 0.5f;

    float rx[NLEVELS], ry[NLEVELS];

#pragma unroll
    for (int l = 0; l < NLEVELS; ++l) {
        const float scale = (float)((16u << l) - 1u);   // exactly representable

        // pos = x01*scale + 0.5 : two separately-rounded ops (NO fma)
        const float px = __fadd_rn(__fmul_rn(x01, scale), 0.5f);
        const float py = __fadd_rn(__fmul_rn(y01, scale), 0.5f);
        const float pz = __fadd_rn(__fmul_rn(z01, scale), 0.5f);

        const float fxf = floorf(px), fyf = floorf(py), fzf = floorf(pz);
        const float tx = px - fxf, ty = py - fyf, tz = pz - fzf;  // exact sub
        const uint32_t ix = (uint32_t)fxf, iy = (uint32_t)fyf, iz = (uint32_t)fzf;
        const float wx0 = 1.0f - tx, wy0 = 1.0f - ty, wz0 = 1.0f - tz;

        const float2* __restrict__ tb = (l == 0)
            ? (const float2*)embeddings
            : ((const float2*)table) + (offs[l] - 4920u);

        uint32_t i0, i1, i2, i3, i4, i5, i6, i7;  // corner bit0=x bit1=y bit2=z
        if (l < 3) {
            const uint32_t s  = (16u << l) + 1u;
            const uint32_t ss = s * s;
            const uint32_t oy0 = iy * s,  oy1 = oy0 + s;
            const uint32_t oz0 = iz * ss, oz1 = oz0 + ss;
            // dense: idx < (res+1)^3 <= hsz, mod is a no-op (x01 in [0.5,1))
            i0 = ix + oy0 + oz0;      i1 = i0 + 1u;
            i2 = ix + oy1 + oz0;      i3 = i2 + 1u;
            i4 = ix + oy0 + oz1;      i5 = i4 + 1u;
            i6 = ix + oy1 + oz1;      i7 = i6 + 1u;
        } else {
            const uint32_t hy0 = iy * PRIME1, hy1 = hy0 + PRIME1;  // uint32 wrap
            const uint32_t hz0 = iz * PRIME2, hz1 = hz0 + PRIME2;
            const uint32_t a00 = hy0 ^ hz0, a10 = hy1 ^ hz0;
            const uint32_t a01 = hy0 ^ hz1, a11 = hy1 ^ hz1;
            i0 = (ix ^ a00) & HASH_MASK;  i1 = ((ix + 1u) ^ a00) & HASH_MASK;
            i2 = (ix ^ a10) & HASH_MASK;  i3 = ((ix + 1u) ^ a10) & HASH_MASK;
            i4 = (ix ^ a01) & HASH_MASK;  i5 = ((ix + 1u) ^ a01) & HASH_MASK;
            i6 = (ix ^ a11) & HASH_MASK;  i7 = ((ix + 1u) ^ a11) & HASH_MASK;
        }

        // 8 independent 8B gathers (ILP; latency hidden by occupancy)
        const float2 e0 = tb[i0], e1 = tb[i1], e2 = tb[i2], e3 = tb[i3];
        const float2 e4 = tb[i4], e5 = tb[i5], e6 = tb[i6], e7 = tb[i7];

        // weights: ((x)*(y))*(z) product order = jnp.prod over last axis
        const float wxy00 = __fmul_rn(wx0, wy0), wxy10 = __fmul_rn(tx, wy0);
        const float wxy01 = __fmul_rn(wx0, ty),  wxy11 = __fmul_rn(tx, ty);
        const float w0 = __fmul_rn(wxy00, wz0), w1 = __fmul_rn(wxy10, wz0);
        const float w2 = __fmul_rn(wxy01, wz0), w3 = __fmul_rn(wxy11, wz0);
        const float w4 = __fmul_rn(wxy00, tz),  w5 = __fmul_rn(wxy10, tz);
        const float w6 = __fmul_rn(wxy01, tz),  w7 = __fmul_rn(wxy11, tz);

        // accumulation order is rounding-insensitive at this threshold
        float r0 = __fmul_rn(w0, e0.x);
        r0 = fmaf(w1, e1.x, r0); r0 = fmaf(w2, e2.x, r0); r0 = fmaf(w3, e3.x, r0);
        r0 = fmaf(w4, e4.x, r0); r0 = fmaf(w5, e5.x, r0); r0 = fmaf(w6, e6.x, r0);
        r0 = fmaf(w7, e7.x, r0);
        float r1 = __fmul_rn(w0, e0.y);
        r1 = fmaf(w1, e1.y, r1); r1 = fmaf(w2, e2.y, r1); r1 = fmaf(w3, e3.y, r1);
        r1 = fmaf(w4, e4.y, r1); r1 = fmaf(w5, e5.y, r1); r1 = fmaf(w6, e6.y, r1);
        r1 = fmaf(w7, e7.y, r1);

        rx[l] = r0;
        ry[l] = r1;
    }

    // out[b, l*2+c]; 8x float4 stores (16B, aligned: 128B per row)
    float4* o = (float4*)(out + (size_t)b * 32);
#pragma unroll
    for (int k = 0; k < 8; ++k) {
        o[k] = make_float4(rx[2 * k], ry[2 * k], rx[2 * k + 1], ry[2 * k + 1]);
    }
}

extern "C" void kernel_launch(void* const* d_in, const int* in_sizes, int n_in,
                              void* d_out, int out_size, void* d_ws, size_t ws_size,
                              hipStream_t stream) {
    const float* inputs     = (const float*)d_in[0];
    const float* embeddings = (const float*)d_in[1];
    const float* table      = (const float*)d_in[2];
    float* out              = (float*)d_out;

    const int B = in_sizes[0] / 3;
    const int grid = (B + 255) / 256;
    grid_encode_kernel<<<grid, 256, 0, stream>>>(inputs, embeddings, table, out, B);
}

// Round 2
// 1292.914 us; speedup vs baseline: 1.3433x; 1.3433x over previous
//
#include <hip/hip_runtime.h>
#include <cstdint>

// Instant-NGP hash-grid encoder, D=3, L=16, C=2, H=16, PS=2, T=2^19.
// Round-2 restructure: level-major execution with XCD pinning.
//   - grid = 16 levels x chunks; blockIdx%8 picks XCD (HW round-robin
//     heuristic), each XCD sweeps its 2 assigned levels sequentially so its
//     4 MB L2 holds exactly one <=4MB level table at a time (kills the
//     4.8 GB L2-thrash refetch seen in round 1).
//   - results staged level-major in ws (coalesced), then LDS-transposed to
//     out[B][32] (avoids 8x partial-sector write amplification).
//   - 4 points/thread => 32 gathers in flight per lane (latency hiding).
// NUMERICS: pos = x01*scale + 0.5 must be two separately-rounded f32 ops
// (numpy semantics); __fmul_rn/__fadd_rn block FMA contraction there.

static constexpr uint32_t PRIME1 = 2654435761u;
static constexpr uint32_t PRIME2 = 805459861u;
static constexpr uint32_t HASH_MASK = (1u << 19) - 1u;

__constant__ uint32_t c_offs[16] = {
    0u, 4920u, 40864u, 315496u, 839784u, 1364072u, 1888360u, 2412648u,
    2936936u, 3461224u, 3985512u, 4509800u, 5034088u, 5558376u,
    6082664u, 6606952u};

__global__ __launch_bounds__(256) void gather_kernel(
    const float* __restrict__ inputs,      // [B,3]
    const float* __restrict__ embeddings,  // [4920,2] (level-0 rows)
    const float* __restrict__ table,       // [TOTAL-4920,2]
    float2* __restrict__ dst,              // staged: ws[l*B + b] ; direct: out_f2[b*16 + l]
    int B, int chunks, int directOut)
{
    // --- block -> (level, chunk) with XCD pinning ---
    const int j   = blockIdx.x;
    const int xcd = j & 7;
    const int s   = j >> 3;
    const int lvl = 2 * xcd + (s >= chunks ? 1 : 0);
    const int chunk = (s >= chunks) ? (s - chunks) : s;
    const int base  = chunk * 1024;           // 4 points/thread * 256 threads
    const int tid   = threadIdx.x;

    // --- stage this chunk's inputs through LDS (coalesced) ---
    __shared__ float sIn[3072];
    {
        const float* gp = inputs + (size_t)base * 3;
        const int lim = B * 3 - base * 3;
#pragma unroll
        for (int k = 0; k < 12; ++k) {
            const int i = tid + k * 256;
            if (i < lim) sIn[i] = gp[i];
        }
    }
    __syncthreads();

    // --- level-dependent constants (block-uniform) ---
    const float scale = (float)((16u << lvl) - 1u);   // exactly representable
    const uint32_t off = c_offs[lvl];
    const float2* __restrict__ tb = (lvl == 0)
        ? (const float2*)embeddings
        : ((const float2*)table) + (off - 4920u);
    const bool dense = (lvl < 3);
    const uint32_t dstr  = (16u << lvl) + 1u;   // dense row stride
    const uint32_t dstr2 = dstr * dstr;

    uint32_t idx[4][8];
    float wts[4][8];

#pragma unroll
    for (int p = 0; p < 4; ++p) {
        const int li = p * 256 + tid;           // local point index
        // bound=1: x01=(x+1)/2 (add rounds once, *0.5 exact)
        const float x01 = __fadd_rn(sIn[li * 3 + 0], 1.0f) * 0.5f;
        const float y01 = __fadd_rn(sIn[li * 3 + 1], 1.0f) * 0.5f;
        const float z01 = __fadd_rn(sIn[li * 3 + 2], 1.0f) * 0.5f;

        // pos = x01*scale + 0.5 : two separately-rounded ops (NO fma)
        const float px = __fadd_rn(__fmul_rn(x01, scale), 0.5f);
        const float py = __fadd_rn(__fmul_rn(y01, scale), 0.5f);
        const float pz = __fadd_rn(__fmul_rn(z01, scale), 0.5f);

        const float fxf = floorf(px), fyf = floorf(py), fzf = floorf(pz);
        const float tx = px - fxf, ty = py - fyf, tz = pz - fzf;  // exact
        const uint32_t ix = (uint32_t)fxf, iy = (uint32_t)fyf, iz = (uint32_t)fzf;
        const float wx0 = 1.0f - tx, wy0 = 1.0f - ty, wz0 = 1.0f - tz;

        if (dense) {
            const uint32_t oy0 = iy * dstr,  oy1 = oy0 + dstr;
            const uint32_t oz0 = iz * dstr2, oz1 = oz0 + dstr2;
            idx[p][0] = ix + oy0 + oz0;  idx[p][1] = idx[p][0] + 1u;
            idx[p][2] = ix + oy1 + oz0;  idx[p][3] = idx[p][2] + 1u;
            idx[p][4] = ix + oy0 + oz1;  idx[p][5] = idx[p][4] + 1u;
            idx[p][6] = ix + oy1 + oz1;  idx[p][7] = idx[p][6] + 1u;
        } else {
            const uint32_t hy0 = iy * PRIME1, hy1 = hy0 + PRIME1;  // u32 wrap
            const uint32_t hz0 = iz * PRIME2, hz1 = hz0 + PRIME2;
            const uint32_t a00 = hy0 ^ hz0, a10 = hy1 ^ hz0;
            const uint32_t a01 = hy0 ^ hz1, a11 = hy1 ^ hz1;
            idx[p][0] = (ix ^ a00) & HASH_MASK;  idx[p][1] = ((ix + 1u) ^ a00) & HASH_MASK;
            idx[p][2] = (ix ^ a10) & HASH_MASK;  idx[p][3] = ((ix + 1u) ^ a10) & HASH_MASK;
            idx[p][4] = (ix ^ a01) & HASH_MASK;  idx[p][5] = ((ix + 1u) ^ a01) & HASH_MASK;
            idx[p][6] = (ix ^ a11) & HASH_MASK;  idx[p][7] = ((ix + 1u) ^ a11) & HASH_MASK;
        }

        // weights: ((x)*(y))*(z) product order matches jnp.prod
        const float wxy00 = __fmul_rn(wx0, wy0), wxy10 = __fmul_rn(tx, wy0);
        const float wxy01 = __fmul_rn(wx0, ty),  wxy11 = __fmul_rn(tx, ty);
        wts[p][0] = __fmul_rn(wxy00, wz0); wts[p][1] = __fmul_rn(wxy10, wz0);
        wts[p][2] = __fmul_rn(wxy01, wz0); wts[p][3] = __fmul_rn(wxy11, wz0);
        wts[p][4] = __fmul_rn(wxy00, tz);  wts[p][5] = __fmul_rn(wxy10, tz);
        wts[p][6] = __fmul_rn(wxy01, tz);  wts[p][7] = __fmul_rn(wxy11, tz);
    }

    // --- issue all 32 gathers before consuming (MLP) ---
    float2 e[4][8];
#pragma unroll
    for (int p = 0; p < 4; ++p)
#pragma unroll
        for (int c = 0; c < 8; ++c)
            e[p][c] = tb[idx[p][c]];

    // --- combine + write ---
#pragma unroll
    for (int p = 0; p < 4; ++p) {
        const int b = base + p * 256 + tid;
        if (b >= B) continue;
        float r0 = __fmul_rn(wts[p][0], e[p][0].x);
        float r1 = __fmul_rn(wts[p][0], e[p][0].y);
#pragma unroll
        for (int c = 1; c < 8; ++c) {
            r0 = fmaf(wts[p][c], e[p][c].x, r0);
            r1 = fmaf(wts[p][c], e[p][c].y, r1);
        }
        if (directOut) {
            dst[(size_t)b * 16 + lvl] = make_float2(r0, r1);
        } else {
            dst[(size_t)lvl * B + b] = make_float2(r0, r1);
        }
    }
}

// ws[16][B] float2 (level-major)  ->  out[B][32] float (point-major)
__global__ __launch_bounds__(256) void transpose_kernel(
    const float2* __restrict__ ws, float* __restrict__ out, int B)
{
    __shared__ float sT[256 * 34];   // pad +2 floats: 2-way LDS aliasing only
    const int tid = threadIdx.x;
    const int b0  = blockIdx.x * 256;

#pragma unroll
    for (int l = 0; l < 16; ++l) {
        const int b = b0 + tid;
        float2 v = make_float2(0.f, 0.f);
        if (b < B) v = ws[(size_t)l * B + b];
        sT[tid * 34 + 2 * l]     = v.x;
        sT[tid * 34 + 2 * l + 1] = v.y;
    }
    __syncthreads();

    float2* orow = (float2*)(out + (size_t)b0 * 32);
    const int lim = (B - b0) * 16;          // valid float2 count in tile
#pragma unroll
    for (int it = 0; it < 16; ++it) {
        const int f = it * 256 + tid;       // float2 index within tile
        if (f < lim) {
            const int p = f >> 4;           // point within tile
            const int c = (f & 15) * 2;     // float column
            orow[f] = make_float2(sT[p * 34 + c], sT[p * 34 + c + 1]);
        }
    }
}

extern "C" void kernel_launch(void* const* d_in, const int* in_sizes, int n_in,
                              void* d_out, int out_size, void* d_ws, size_t ws_size,
                              hipStream_t stream) {
    const float* inputs     = (const float*)d_in[0];
    const float* embeddings = (const float*)d_in[1];
    const float* table      = (const float*)d_in[2];
    float* out              = (float*)d_out;

    const int B = in_sizes[0] / 3;
    const int chunks = (B + 1023) / 1024;
    const size_t need = (size_t)16 * (size_t)B * sizeof(float2);
    const bool staged = ws_size >= need;

    gather_kernel<<<16 * chunks, 256, 0, stream>>>(
        inputs, embeddings, table,
        staged ? (float2*)d_ws : (float2*)d_out,
        B, chunks, staged ? 0 : 1);

    if (staged) {
        transpose_kernel<<<(B + 255) / 256, 256, 0, stream>>>(
            (const float2*)d_ws, out, B);
    }
}